// Round 4
// baseline (1080.011 us; speedup 1.0000x reference)
//
#include <hip/hip_runtime.h>

#define NN 20000

typedef __attribute__((ext_vector_type(8))) short frag8;
typedef __attribute__((ext_vector_type(4))) float f32x4;

struct NbrPtrs { const int* p[9]; };
struct Cont3  { const float* c[3]; };

__device__ inline float bf2f(unsigned short u){ union{unsigned i; float f;} v; v.i=(unsigned)u<<16; return v.f; }
__device__ inline unsigned short f2bf(float f){ union{float f; unsigned i;} v; v.f=f;
  return (unsigned short)((v.i + 0x7fffu + ((v.i>>16)&1u)) >> 16); }
__device__ inline float sigm(float x){ return 1.f/(1.f+__expf(-x)); }
__device__ inline float tanh_(float x){ return 1.f - 2.f/(__expf(2.f*x)+1.f); }

// ---- pack weights f32 -> bf16 MFMA-B-fragment layout ----
// WihF per LD: [kk(4)][g(4)][m(4)][u(64)][j(8)]  k=kk*32+m*8+j, col=g*64+u
// WhhF per LD: [kk(2)][g(4)][m(4)][u(64)][j(8)]  k=kk*32+m*8+j, col=g*64+u
__global__ void pack_kernel(const float* __restrict__ Wih, const float* __restrict__ Whh,
                            const float* __restrict__ bsrc,
                            unsigned short* __restrict__ WihF, unsigned short* __restrict__ WhhF,
                            float* __restrict__ biasF)
{
  const int NW = 12*32768, NH2 = 12*16384, NB = 12*256;
  const int total = NW + NH2 + NB;
  for (int i = blockIdx.x*blockDim.x + threadIdx.x; i < total; i += gridDim.x*blockDim.x) {
    if (i < NW) {
      int LD=i>>15, r=i&32767;
      int j=r&7, u=(r>>3)&63, m=(r>>9)&3, g=(r>>11)&3, kk=(r>>13)&3;
      WihF[i] = f2bf(Wih[((long)LD*256 + g*64+u)*128 + kk*32+m*8+j]);
    } else if (i < NW+NH2) {
      int e=i-NW, LD=e>>14, r=e&16383;
      int j=r&7, u=(r>>3)&63, m=(r>>9)&3, g=(r>>11)&3, kk=(r>>13)&1;
      WhhF[e] = f2bf(Whh[((long)LD*256 + g*64+u)*64 + kk*32+m*8+j]);
    } else {
      int e=i-NW-NH2;
      biasF[e] = bsrc[e];
    }
  }
}

// ---- fused BiLSTM-mean; block = 4 waves = one 16-node tile; wave w owns units [16w,16w+16) ----
template<int T, int ISC3>
__global__ __launch_bounds__(256, 2) void lstm_kernel(
    Cont3 xf, const unsigned short* __restrict__ xb,
    NbrPtrs nb, int dtype,
    const unsigned short* __restrict__ WihF, const unsigned short* __restrict__ WhhF,
    const float* __restrict__ biasF, unsigned short* __restrict__ outH)
{
  const int y = blockIdx.y, dir = y & 1, s = y >> 1;   // s: content type (C2) or source type (C3)
  const int L = ISC3 ? 3 + s : s;
  const int* nbr = ISC3 ? nb.p[dtype*3 + s] : nullptr;
  const unsigned short* xbase16 = ISC3 ? xb + (long)s*NN*128 : nullptr;
  const float* xbase32 = ISC3 ? nullptr : xf.c[s];
  unsigned short* outp = outH + (long)s*NN*128;
  const int lane = threadIdx.x & 63, w = threadIdx.x >> 6;
  const int m = lane >> 4, q = lane & 15;
  const int LD = L*2 + dir;

  const unsigned short* wp = WihF + (long)LD*32768;
  const unsigned short* hp = WhhF + (long)LD*16384;
  frag8 Bp[4][4], Br[2][4];
#pragma unroll
  for (int kk=0;kk<4;kk++)
#pragma unroll
    for (int g=0;g<4;g++)
      Bp[kk][g] = *(const frag8*)(wp + ((((kk*4+g)*4 + m)*64) + w*16 + q)*8);
#pragma unroll
  for (int kk=0;kk<2;kk++)
#pragma unroll
    for (int g=0;g<4;g++)
      Br[kk][g] = *(const frag8*)(hp + ((((kk*4+g)*4 + m)*64) + w*16 + q)*8);
  float bias[4];
#pragma unroll
  for (int g=0;g<4;g++) bias[g] = biasF[LD*256 + g*64 + w*16 + q];

  __shared__ __align__(16) unsigned short Hlds[1024];  // [16 nodes][64 units] bf16, XOR-swizzled

  for (int tile = blockIdx.x; tile < NN/16; tile += gridDim.x) {
    const int node0 = tile*16;
    ((uint2*)Hlds)[threadIdx.x] = make_uint2(0u,0u);
    __syncthreads();
    f32x4 cst = {0.f,0.f,0.f,0.f}, hsum = {0.f,0.f,0.f,0.f};
    for (int t=0; t<T; t++) {
      const int tt = dir ? (T-1-t) : t;
      frag8 Xf[4];
      if (ISC3) {
        int idx = nbr[(node0+q)*10 + tt];
        const unsigned short* xr = xbase16 + (long)idx*128;
#pragma unroll
        for (int kk=0;kk<4;kk++) Xf[kk] = *(const frag8*)(xr + kk*32 + m*8);
      } else {
        const float* xr = xbase32 + ((long)(node0+q)*3 + tt)*128;
#pragma unroll
        for (int kk=0;kk<4;kk++) {
          float4 f0 = *(const float4*)(xr + kk*32 + m*8);
          float4 f1 = *(const float4*)(xr + kk*32 + m*8 + 4);
          frag8 xv;
          xv[0]=(short)f2bf(f0.x); xv[1]=(short)f2bf(f0.y); xv[2]=(short)f2bf(f0.z); xv[3]=(short)f2bf(f0.w);
          xv[4]=(short)f2bf(f1.x); xv[5]=(short)f2bf(f1.y); xv[6]=(short)f2bf(f1.z); xv[7]=(short)f2bf(f1.w);
          Xf[kk] = xv;
        }
      }
      f32x4 acc[4];
#pragma unroll
      for (int g=0;g<4;g++) acc[g] = (f32x4){bias[g],bias[g],bias[g],bias[g]};
#pragma unroll
      for (int kk=0;kk<4;kk++)
#pragma unroll
        for (int g=0;g<4;g++)
          acc[g] = __builtin_amdgcn_mfma_f32_16x16x32_bf16(Xf[kk], Bp[kk][g], acc[g], 0,0,0);
#pragma unroll
      for (int kk=0;kk<2;kk++) {
        frag8 Ah = *(const frag8*)((const char*)Hlds + (q*128 + ((kk*64 + m*16) ^ ((q&7)<<4))));
#pragma unroll
        for (int g=0;g<4;g++)
          acc[g] = __builtin_amdgcn_mfma_f32_16x16x32_bf16(Ah, Br[kk][g], acc[g], 0,0,0);
      }
      __syncthreads();   // all waves done reading H(t-1)
#pragma unroll
      for (int r=0;r<4;r++) {
        float gi = sigm(acc[0][r]);
        float gf = sigm(acc[1][r]);
        float gg = tanh_(acc[2][r]);
        float go = sigm(acc[3][r]);
        float cc = gf*cst[r] + gi*gg;
        cst[r] = cc;
        float h = go*tanh_(cc);
        hsum[r] += h;
        int row = m*4 + r;           // node row (C-frag: row=(lane>>4)*4+reg)
        int u = w*16 + q;            // unit    (C-frag: col=lane&15)
        *(unsigned short*)((char*)Hlds + (row*128 + ((2*u) ^ ((row&7)<<4)))) = f2bf(h);
      }
      __syncthreads();   // H(t) visible
    }
#pragma unroll
    for (int r=0;r<4;r++) {
      int node = node0 + m*4 + r;
      outp[(long)node*128 + dir*64 + w*16 + q] = f2bf(hsum[r]*(1.f/T));
    }
  }
}

// ---- attention fusion for one destination type; OUTPUT IS FLOAT32 ----
__global__ __launch_bounds__(256) void attn_kernel(
    const unsigned short* __restrict__ ch, const unsigned short* __restrict__ nh,
    const float* __restrict__ awd, const float* __restrict__ ab, int d,
    float* __restrict__ outp)
{
  int i = blockIdx.x*4 + (threadIdx.x >> 6);
  if (i >= NN) return;
  int lane = threadIdx.x & 63;
  const float2 wlo = *(const float2*)(awd + 2*lane);          // dims [0,128): dot with self
  const float2 whi = *(const float2*)(awd + 128 + 2*lane);    // dims [128,256): dot with emb
  unsigned sv = *(const unsigned*)(ch + (long)i*128 + 2*lane);
  float sx = bf2f((unsigned short)sv), sy = bf2f((unsigned short)(sv>>16));
  float ex[3], ey[3];
#pragma unroll
  for (int k=0;k<3;k++) {
    unsigned v = *(const unsigned*)(nh + ((long)k*NN + i)*128 + 2*lane);
    ex[k]=bf2f((unsigned short)v); ey[k]=bf2f((unsigned short)(v>>16));
  }
  float pd = sx*wlo.x + sy*wlo.y;
  float p[4];
#pragma unroll
  for (int k=0;k<3;k++) p[k] = ex[k]*whi.x + ey[k]*whi.y;
  p[3] = sx*whi.x + sy*whi.y;
#pragma unroll
  for (int off=1; off<64; off<<=1) {
    pd  += __shfl_xor(pd , off, 64);
    p[0]+= __shfl_xor(p[0],off, 64);
    p[1]+= __shfl_xor(p[1],off, 64);
    p[2]+= __shfl_xor(p[2],off, 64);
    p[3]+= __shfl_xor(p[3],off, 64);
  }
  float b = ab[d];
  float sc[4], mx=-1e30f;
#pragma unroll
  for (int k=0;k<4;k++){ float v = pd + p[k] + b; sc[k] = v>0.f ? v : 0.01f*v; mx = fmaxf(mx, sc[k]); }
  float es=0.f;
#pragma unroll
  for (int k=0;k<4;k++){ sc[k]=__expf(sc[k]-mx); es+=sc[k]; }
  float inv = 1.f/es;
  float ox = (sc[0]*ex[0]+sc[1]*ex[1]+sc[2]*ex[2]+sc[3]*sx)*inv;
  float oy = (sc[0]*ey[0]+sc[1]*ey[1]+sc[2]*ey[2]+sc[3]*sy)*inv;
  *(float2*)(outp + (long)i*128 + 2*lane) = make_float2(ox, oy);
}

extern "C" void kernel_launch(void* const* d_in, const int* in_sizes, int n_in,
                              void* d_out, int out_size, void* d_ws, size_t ws_size,
                              hipStream_t stream)
{
  Cont3 cc;
  cc.c[0] = (const float*)d_in[0];
  cc.c[1] = (const float*)d_in[1];
  cc.c[2] = (const float*)d_in[2];
  NbrPtrs nb;
  for (int k=0;k<9;k++) nb.p[k] = (const int*)d_in[3+k];
  const float* Wih = (const float*)d_in[12];
  const float* Whh = (const float*)d_in[13];
  const float* bb  = (const float*)d_in[14];
  const float* aw  = (const float*)d_in[15];
  const float* ab  = (const float*)d_in[16];

  char* wsp = (char*)d_ws;
  unsigned short* WihF = (unsigned short*)wsp;     wsp += 786432;
  unsigned short* WhhF = (unsigned short*)wsp;     wsp += 393216;
  float* biasF = (float*)wsp;                      wsp += 12288;
  unsigned short* contentH = (unsigned short*)wsp; wsp += 15360000;
  unsigned short* scratch  = (unsigned short*)wsp; // 15360000 B; total ~30.4 MiB

  pack_kernel<<<1024, 256, 0, stream>>>(Wih, Whh, bb, WihF, WhhF, biasF);
  lstm_kernel<3,0><<<dim3(250,6), 256, 0, stream>>>(cc, nullptr, nb, 0, WihF, WhhF, biasF, contentH);
  for (int d=0; d<3; d++) {
    lstm_kernel<10,1><<<dim3(250,6), 256, 0, stream>>>(cc, contentH, nb, d, WihF, WhhF, biasF, scratch);
    attn_kernel<<<NN/4, 256, 0, stream>>>(contentH + (long)d*NN*128, scratch,
                                          aw + d*256, ab, d,
                                          (float*)d_out + (long)d*NN*128);
  }
}

// Round 5
// 954.212 us; speedup vs baseline: 1.1318x; 1.1318x over previous
//
#include <hip/hip_runtime.h>

#define NN 20000
#define LOG2E 1.44269504088896f

typedef __attribute__((ext_vector_type(8))) short frag8;
typedef __attribute__((ext_vector_type(4))) float f32x4;

struct NbrPtrs { const int* p[9]; };
struct Cont3  { const float* c[3]; };

__device__ inline float bf2f(unsigned short u){ union{unsigned i; float f;} v; v.i=(unsigned)u<<16; return v.f; }
__device__ inline unsigned short f2bf(float f){ union{float f; unsigned i;} v; v.f=f;
  return (unsigned short)((v.i + 0x7fffu + ((v.i>>16)&1u)) >> 16); }
__device__ inline unsigned cvtpk(float a, float b){ unsigned r;
  asm("v_cvt_pk_bf16_f32 %0, %1, %2" : "=v"(r) : "v"(a), "v"(b)); return r; }

// ---- pack: weights -> per-(LD,wave) contiguous 24KB fragment slices; biases pre-scaled ----
// WF[LD(12)][w(4)][fi(24)][lane(64)][j(8)]: fi<16: Wih kk=fi>>2,g=fi&3; fi>=16: Whh kk,g of fi-16
// element: col = g*64 + w*16 + (lane&15), k = kk*32 + (lane>>4)*8 + j
__global__ void pack_kernel(const float* __restrict__ Wih, const float* __restrict__ Whh,
                            const float* __restrict__ bsrc,
                            unsigned short* __restrict__ WF, float* __restrict__ biasB)
{
  const int NWF = 589824, NB = 3072;
  for (int e = blockIdx.x*blockDim.x + threadIdx.x; e < NWF+NB; e += gridDim.x*blockDim.x) {
    if (e < NWF) {
      int t = e >> 9, r = e & 511;
      int lane = r >> 3, j = r & 7;
      int fi = t % 24, s2 = t / 24;
      int w = s2 & 3, LD = s2 >> 2;
      int m = lane >> 4, q = lane & 15;
      float v;
      if (fi < 16) {
        int kk = fi >> 2, g = fi & 3;
        v = Wih[((long)LD*256 + g*64 + w*16 + q)*128 + kk*32 + m*8 + j];
      } else {
        int f2 = fi - 16, kk = f2 >> 2, g = f2 & 3;
        v = Whh[((long)LD*256 + g*64 + w*16 + q)*64 + kk*32 + m*8 + j];
      }
      WF[e] = f2bf(v);
    } else {
      int e2 = e - NWF;
      int g = (e2 >> 6) & 3;
      float b = bsrc[e2];
      biasB[e2] = (g==2) ? b*(2.f*LOG2E) : -b*LOG2E;   // folded into exp2 args
    }
  }
}

__device__ inline frag8 load_x_f32(const float* xr, int off){
  float4 f0 = *(const float4*)(xr + off);
  float4 f1 = *(const float4*)(xr + off + 4);
  union { frag8 f; unsigned u[4]; } r;
  r.u[0]=cvtpk(f0.x,f0.y); r.u[1]=cvtpk(f0.z,f0.w);
  r.u[2]=cvtpk(f1.x,f1.y); r.u[3]=cvtpk(f1.z,f1.w);
  return r.f;
}

// ---- BiLSTM-mean: 4 waves = 16-node tile; wave w owns units [16w,16w+16), weights in REGISTERS ----
template<int T, int ISC3>
__global__ __launch_bounds__(256) void lstm2(
    Cont3 xf, const unsigned short* __restrict__ xb, NbrPtrs nb,
    const unsigned short* __restrict__ WF, const float* __restrict__ biasB,
    unsigned short* __restrict__ outH)
{
  const int y = blockIdx.y, dir = y & 1, sl = y >> 1;   // sl: C2 type / C3 relation (d*3+s)
  const int s = ISC3 ? (sl % 3) : sl;
  const int LD = (ISC3 ? 3 + s : s)*2 + dir;
  const int* nbr = ISC3 ? nb.p[sl] : nullptr;
  const unsigned short* xb16 = ISC3 ? xb + (long)s*NN*128 : nullptr;
  const float* xb32 = ISC3 ? nullptr : xf.c[s];
  unsigned short* outp = outH + (long)sl*NN*128;

  const int tid = threadIdx.x, lane = tid & 63, w = tid >> 6;
  const int m = lane >> 4, q = lane & 15;

  __shared__ __align__(16) char lds[24576];   // staging buffer, then reused as H double-buffer

  // stage weights through LDS (4 rounds), read own slice to regs; LDS then clobbered by H
  frag8 Bp[4][4], Br[2][4];
  for (int rr = 0; rr < 4; rr++) {
    const uint4* src = (const uint4*)(WF + ((long)(LD*4 + rr)*24)*512);
#pragma unroll
    for (int it = 0; it < 6; it++)
      ((uint4*)lds)[tid + it*256] = src[tid + it*256];
    __syncthreads();
    if (w == rr) {
#pragma unroll
      for (int fi = 0; fi < 16; fi++)
        Bp[fi>>2][fi&3] = *(const frag8*)(lds + fi*1024 + lane*16);
#pragma unroll
      for (int fi = 16; fi < 24; fi++)
        Br[(fi-16)>>2][(fi-16)&3] = *(const frag8*)(lds + fi*1024 + lane*16);
    }
    __syncthreads();
  }
  const float bI = biasB[LD*256 +   0 + w*16 + q];
  const float bF = biasB[LD*256 +  64 + w*16 + q];
  const float bG = biasB[LD*256 + 128 + w*16 + q];
  const float bO = biasB[LD*256 + 192 + w*16 + q];

  // precomputed swizzled H addresses (bufs at 0 / 2048)
  int rd[2][2], wra[2][4];
#pragma unroll
  for (int kk=0;kk<2;kk++){
    int o = q*128 + ((kk*64 + m*16) ^ ((q&7)<<4));
    rd[0][kk]=o; rd[1][kk]=o+2048;
  }
#pragma unroll
  for (int r=0;r<4;r++){
    int row = m*4 + r, uu = w*16 + q;
    int o = row*128 + ((2*uu) ^ ((row&7)<<4));
    wra[0][r]=o; wra[1][r]=o+2048;
  }
  const int u = w*16 + q;
  const f32x4 Z = {0.f,0.f,0.f,0.f};

  for (int tile = blockIdx.x; tile < NN/16; tile += gridDim.x) {
    const int node0 = tile*16;
    f32x4 cst = {0,0,0,0}, hsum = {0,0,0,0};
    frag8 X[2][4];
    { // preload t=0
      const int tt0 = dir ? (T-1) : 0;
      if (ISC3) {
        int idx = nbr[(node0+q)*10 + tt0];
        const unsigned short* xr = xb16 + (long)idx*128;
#pragma unroll
        for (int kk=0;kk<4;kk++) X[0][kk] = *(const frag8*)(xr + kk*32 + m*8);
      } else {
        const float* xr = xb32 + ((long)(node0+q)*3 + tt0)*128;
#pragma unroll
        for (int kk=0;kk<4;kk++) X[0][kk] = load_x_f32(xr, kk*32 + m*8);
      }
    }
#pragma unroll
    for (int t=0; t<T; t++) {
      const int cb = t & 1, nb2 = cb ^ 1;
      f32x4 acc[4];
#pragma unroll
      for (int g=0;g<4;g++)
        acc[g] = __builtin_amdgcn_mfma_f32_16x16x32_bf16(X[cb][0], Bp[0][g], Z, 0,0,0);
#pragma unroll
      for (int kk=1;kk<4;kk++)
#pragma unroll
        for (int g=0;g<4;g++)
          acc[g] = __builtin_amdgcn_mfma_f32_16x16x32_bf16(X[cb][kk], Bp[kk][g], acc[g], 0,0,0);
      if (t > 0) {                       // h(0)=0: skip recurrence at t=0
#pragma unroll
        for (int kk=0;kk<2;kk++) {
          frag8 Ah = *(const frag8*)(lds + rd[cb][kk]);
#pragma unroll
          for (int g=0;g<4;g++)
            acc[g] = __builtin_amdgcn_mfma_f32_16x16x32_bf16(Ah, Br[kk][g], acc[g], 0,0,0);
        }
      }
      if (t+1 < T) {                     // prefetch X(t+1) under gate math
        const int tt = dir ? (T-2-t) : (t+1);
        if (ISC3) {
          int idx = nbr[(node0+q)*10 + tt];
          const unsigned short* xr = xb16 + (long)idx*128;
#pragma unroll
          for (int kk=0;kk<4;kk++) X[nb2][kk] = *(const frag8*)(xr + kk*32 + m*8);
        } else {
          const float* xr = xb32 + ((long)(node0+q)*3 + tt)*128;
#pragma unroll
          for (int kk=0;kk<4;kk++) X[nb2][kk] = load_x_f32(xr, kk*32 + m*8);
        }
      }
#pragma unroll
      for (int r=0;r<4;r++) {
        float gi = __builtin_amdgcn_rcpf(1.f + __builtin_amdgcn_exp2f(fmaf(acc[0][r], -LOG2E, bI)));
        float gf = __builtin_amdgcn_rcpf(1.f + __builtin_amdgcn_exp2f(fmaf(acc[1][r], -LOG2E, bF)));
        float tg = fmaf(-2.f, __builtin_amdgcn_rcpf(1.f + __builtin_amdgcn_exp2f(fmaf(acc[2][r], 2.f*LOG2E, bG))), 1.f);
        float go = __builtin_amdgcn_rcpf(1.f + __builtin_amdgcn_exp2f(fmaf(acc[3][r], -LOG2E, bO)));
        float cc = fmaf(gf, cst[r], gi*tg);
        cst[r] = cc;
        float tc = fmaf(-2.f, __builtin_amdgcn_rcpf(1.f + __builtin_amdgcn_exp2f(cc*(2.f*LOG2E))), 1.f);
        float h = go*tc;
        hsum[r] += h;
        *(unsigned short*)(lds + wra[nb2][r]) = (unsigned short)cvtpk(h, h);  // H(t) -> buf (t+1)&1
      }
      __syncthreads();                   // single barrier per step
    }
#pragma unroll
    for (int r=0;r<4;r++) {
      int node = node0 + m*4 + r;
      outp[(long)node*128 + dir*64 + u] = f2bf(hsum[r]*(1.f/T));
    }
  }
}

// ---- attention fusion, all 3 destination types in one launch; f32 output ----
__global__ __launch_bounds__(256) void attn_kernel(
    const unsigned short* __restrict__ ch, const unsigned short* __restrict__ nh,
    const float* __restrict__ aw, const float* __restrict__ ab,
    float* __restrict__ out)
{
  int wid = blockIdx.x*4 + (threadIdx.x >> 6);   // < 3*NN exactly
  int n = wid / NN, i = wid - n*NN;
  int lane = threadIdx.x & 63;
  const float2 wlo = *(const float2*)(aw + n*256 + 2*lane);
  const float2 whi = *(const float2*)(aw + n*256 + 128 + 2*lane);
  unsigned sv = *(const unsigned*)(ch + ((long)n*NN + i)*128 + 2*lane);
  float sx = bf2f((unsigned short)sv), sy = bf2f((unsigned short)(sv>>16));
  float ex[3], ey[3];
#pragma unroll
  for (int k=0;k<3;k++) {
    unsigned v = *(const unsigned*)(nh + ((long)(n*3+k)*NN + i)*128 + 2*lane);
    ex[k]=bf2f((unsigned short)v); ey[k]=bf2f((unsigned short)(v>>16));
  }
  float pd = sx*wlo.x + sy*wlo.y;
  float p[4];
#pragma unroll
  for (int k=0;k<3;k++) p[k] = ex[k]*whi.x + ey[k]*whi.y;
  p[3] = sx*whi.x + sy*whi.y;
#pragma unroll
  for (int off=1; off<64; off<<=1) {
    pd  += __shfl_xor(pd , off, 64);
    p[0]+= __shfl_xor(p[0],off, 64);
    p[1]+= __shfl_xor(p[1],off, 64);
    p[2]+= __shfl_xor(p[2],off, 64);
    p[3]+= __shfl_xor(p[3],off, 64);
  }
  float b = ab[n];
  float sc[4], mx=-1e30f;
#pragma unroll
  for (int k=0;k<4;k++){ float v = pd + p[k] + b; sc[k] = v>0.f ? v : 0.01f*v; mx = fmaxf(mx, sc[k]); }
  float es=0.f;
#pragma unroll
  for (int k=0;k<4;k++){ sc[k]=__expf(sc[k]-mx); es+=sc[k]; }
  float inv = 1.f/es;
  float ox = (sc[0]*ex[0]+sc[1]*ex[1]+sc[2]*ex[2]+sc[3]*sx)*inv;
  float oy = (sc[0]*ey[0]+sc[1]*ey[1]+sc[2]*ey[2]+sc[3]*sy)*inv;
  *(float2*)(out + ((long)n*NN + i)*128 + 2*lane) = make_float2(ox, oy);
}

extern "C" void kernel_launch(void* const* d_in, const int* in_sizes, int n_in,
                              void* d_out, int out_size, void* d_ws, size_t ws_size,
                              hipStream_t stream)
{
  Cont3 cc;
  cc.c[0] = (const float*)d_in[0];
  cc.c[1] = (const float*)d_in[1];
  cc.c[2] = (const float*)d_in[2];
  NbrPtrs nb;
  for (int k=0;k<9;k++) nb.p[k] = (const int*)d_in[3+k];
  const float* Wih = (const float*)d_in[12];
  const float* Whh = (const float*)d_in[13];
  const float* bb  = (const float*)d_in[14];
  const float* aw  = (const float*)d_in[15];
  const float* ab  = (const float*)d_in[16];

  char* wsp = (char*)d_ws;
  unsigned short* WF = (unsigned short*)wsp;        wsp += 1179648;
  float* biasB = (float*)wsp;                       wsp += 12288;
  unsigned short* contentH = (unsigned short*)wsp;  wsp += 15360000;
  unsigned short* neighH   = (unsigned short*)wsp;  // 46,080,000 B; total ~62.6 MB

  pack_kernel<<<1024, 256, 0, stream>>>(Wih, Whh, bb, WF, biasB);
  lstm2<3,0><<<dim3(625,6),  256, 0, stream>>>(cc, nullptr,  nb, WF, biasB, contentH);
  lstm2<10,1><<<dim3(625,18),256, 0, stream>>>(cc, contentH, nb, WF, biasB, neighH);
  attn_kernel<<<(3*NN)/4, 256, 0, stream>>>(contentH, neighH, aw, ab, (float*)d_out);
}